// Round 3
// baseline (360.776 us; speedup 1.0000x reference)
//
#include <hip/hip_runtime.h>
#include <hip/hip_bf16.h>
#include <stdint.h>

// Problem constants
#define M_DIM 8192      // 2*4096 flattened batch
#define K_DIM 2048      // ACTIVE (in)
#define N_DIM 2048      // ACTIVE (out)
#define IN_DIM 4096     // ORIG_IN
#define OUT_DIM 4096    // ORIG_OUT
#define SCALING 2.0f    // 32/16

typedef __attribute__((ext_vector_type(8))) short bf16x8_t;   // 8 bf16 = 4 VGPRs
typedef __attribute__((ext_vector_type(4))) float f32x4_t;
typedef __attribute__((ext_vector_type(16))) float f32x16_t;  // 32x32 MFMA acc

__device__ __forceinline__ void load_lds16(const void* gptr, void* lptr) {
    __builtin_amdgcn_global_load_lds(
        (const __attribute__((address_space(1))) uint32_t*)(uintptr_t)gptr,
        (__attribute__((address_space(3))) uint32_t*)(uintptr_t)lptr,
        16, 0, 0);
}

// ---------------------------------------------------------------------------
// Kernel 1: fold LoRA into base weight, cast to bf16.
// ---------------------------------------------------------------------------
__global__ void fold_w_kernel(const float* __restrict__ Wb,
                              const float* __restrict__ lA,   // [16][2048]
                              const float* __restrict__ lB,   // [2048][16]
                              __hip_bfloat16* __restrict__ We) {
    const int k = blockIdx.x * 256 + threadIdx.x;
    const int o = blockIdx.y;
    float acc = Wb[(size_t)o * K_DIM + k];
    #pragma unroll
    for (int r = 0; r < 16; ++r)
        acc += SCALING * lB[o * 16 + r] * lA[r * K_DIM + k];
    We[(size_t)o * K_DIM + k] = __float2bfloat16(acc);
}

// ---------------------------------------------------------------------------
// Kernel 2: gather active input columns + cast to bf16, via LDS staging.
// ---------------------------------------------------------------------------
__global__ void __launch_bounds__(256)
gather_cast_kernel(const float* __restrict__ x,
                   const int* __restrict__ idx,
                   __hip_bfloat16* __restrict__ xs) {
    __shared__ float row[IN_DIM];
    const int n = blockIdx.x;
    const float* xrow = x + (size_t)n * IN_DIM;
    #pragma unroll
    for (int i = 0; i < 4; ++i) {
        const int c = (i * 256 + threadIdx.x) * 4;
        *(float4*)&row[c] = *(const float4*)&xrow[c];
    }
    __syncthreads();
    const int c0 = threadIdx.x * 8;
    int4 i0 = *(const int4*)(idx + c0);
    int4 i1 = *(const int4*)(idx + c0 + 4);
    union { bf16x8_t v; __hip_bfloat16 h[8]; } u;
    u.h[0] = __float2bfloat16(row[i0.x]);
    u.h[1] = __float2bfloat16(row[i0.y]);
    u.h[2] = __float2bfloat16(row[i0.z]);
    u.h[3] = __float2bfloat16(row[i0.w]);
    u.h[4] = __float2bfloat16(row[i1.x]);
    u.h[5] = __float2bfloat16(row[i1.y]);
    u.h[6] = __float2bfloat16(row[i1.z]);
    u.h[7] = __float2bfloat16(row[i1.w]);
    *(bf16x8_t*)(xs + (size_t)n * K_DIM + c0) = u.v;
}

// ---------------------------------------------------------------------------
// Kernel 3: inverse index map (binary search in sorted out_idx).
// ---------------------------------------------------------------------------
__global__ void build_inv_kernel(const int* __restrict__ oidx,
                                 int* __restrict__ inv) {
    const int c = blockIdx.x * 256 + threadIdx.x;   // 0..4095
    int lo = 0, hi = N_DIM;
    while (lo < hi) {
        const int mid = (lo + hi) >> 1;
        if (oidx[mid] < c) lo = mid + 1; else hi = mid;
    }
    inv[c] = (lo < N_DIM && oidx[lo] == c) ? lo : -1;
}

// ---------------------------------------------------------------------------
// Kernel 4: GEMM  C = A @ B^T + bias.  128x128 tile, BK=64, 4 waves (2x2),
// each wave 64x64 via 2x2 MFMA 32x32x16 bf16 (8.07cyc/32KFLOP vs 4.85/16K:
// ~17% fewer MFMA-pipe cycles than 16x16x32 at identical LDS bytes/FLOP).
// global_load_lds 16B staging, XOR chunk swizzle (0 bank conflicts, r1/r2).
// launch_bounds(256,4): force <=128 regs/wave -> 4 blocks/CU (whole grid
// resident) for barrier-stall overlap.
// XCD swizzle: each XCD owns 2 n-tiles -> its 1MB B-slice stays L2-resident.
// ---------------------------------------------------------------------------
template <bool COMPACT>
__global__ void __launch_bounds__(256, 4)
gemm_kernel(const __hip_bfloat16* __restrict__ A,   // [M][K]
            const __hip_bfloat16* __restrict__ B,   // [N][K] (W_eff)
            const float* __restrict__ bias,         // [N]
            const int* __restrict__ oidx,           // [N]
            float* __restrict__ out,                // [M][OUT_DIM] (fallback)
            __hip_bfloat16* __restrict__ Cc)        // [M][N] (compact)
{
    __shared__ __hip_bfloat16 As[128 * 64];
    __shared__ __hip_bfloat16 Bs[128 * 64];

    const int tid  = threadIdx.x;
    const int wave = tid >> 6;
    const int lane = tid & 63;

    // XCD-aware remap: HW linear id l -> xcd = l&7 (round-robin heuristic);
    // xcd owns n-tiles {2*xcd, 2*xcd+1} x all 64 m-tiles.
    const int l   = blockIdx.y * gridDim.x + blockIdx.x;   // 0..1023
    const int xcd = l & 7;
    const int q   = l >> 3;                                 // 0..127
    const int n0  = (xcd * 2 + (q >> 6)) * 128;
    const int m0  = (q & 63) * 128;

    const int wm = (wave >> 1) * 64;
    const int wn = (wave & 1) * 64;

    const int srow  = tid >> 3;        // 0..31
    const int sslot = tid & 7;         // physical 16B slot within row

    const int r31  = lane & 31;
    const int half = lane >> 5;        // 0/1

    f32x16_t acc[2][2] = {};

    for (int k0 = 0; k0 < K_DIM; k0 += 64) {
        #pragma unroll
        for (int it = 0; it < 4; ++it) {
            const int row = it * 32 + srow;
            const int ch = sslot ^ (row & 7);
            const __hip_bfloat16* ga = A + (size_t)(m0 + row) * K_DIM + k0 + ch * 8;
            const __hip_bfloat16* gb = B + (size_t)(n0 + row) * K_DIM + k0 + ch * 8;
            load_lds16(ga, (void*)&As[(it * 32 + wave * 8) * 64]);
            load_lds16(gb, (void*)&Bs[(it * 32 + wave * 8) * 64]);
        }
        __syncthreads();

        #pragma unroll
        for (int ks = 0; ks < 4; ++ks) {   // four K=16 steps within BK=64
            const int ch = ks * 2 + half;  // 16B chunk holding this lane's k
            bf16x8_t af[2], bfr[2];
            #pragma unroll
            for (int i = 0; i < 2; ++i) {
                const int rowa = wm + i * 32 + r31;
                af[i] = *(const bf16x8_t*)&As[rowa * 64 + (ch ^ (rowa & 7)) * 8];
                const int rowb = wn + i * 32 + r31;
                bfr[i] = *(const bf16x8_t*)&Bs[rowb * 64 + (ch ^ (rowb & 7)) * 8];
            }
            #pragma unroll
            for (int i = 0; i < 2; ++i)
                #pragma unroll
                for (int j = 0; j < 2; ++j)
                    acc[i][j] = __builtin_amdgcn_mfma_f32_32x32x16_bf16(
                        af[i], bfr[j], acc[i][j], 0, 0, 0);
        }
        __syncthreads();
    }

    // C/D layout for 32x32 (verified m74/m101):
    //   col = lane&31, row = (reg&3) + 8*(reg>>2) + 4*(lane>>5)
    #pragma unroll
    for (int j = 0; j < 2; ++j) {
        const int gn = n0 + wn + j * 32 + r31;
        const float bv = bias[gn];
        if (COMPACT) {
            #pragma unroll
            for (int i = 0; i < 2; ++i) {
                #pragma unroll
                for (int reg = 0; reg < 16; ++reg) {
                    const int gm = m0 + wm + i * 32 +
                                   (reg & 3) + 8 * (reg >> 2) + 4 * half;
                    Cc[(size_t)gm * N_DIM + gn] =
                        __float2bfloat16(acc[i][j][reg] + bv);
                }
            }
        } else {
            const int oc = oidx[gn];
            #pragma unroll
            for (int i = 0; i < 2; ++i) {
                #pragma unroll
                for (int reg = 0; reg < 16; ++reg) {
                    const int gm = m0 + wm + i * 32 +
                                   (reg & 3) + 8 * (reg >> 2) + 4 * half;
                    out[(size_t)gm * OUT_DIM + oc] = acc[i][j][reg] + bv;
                }
            }
        }
    }
}

// ---------------------------------------------------------------------------
// Kernel 5: expand compact C into full output (zeros for unselected cols).
// ---------------------------------------------------------------------------
__global__ void __launch_bounds__(256)
scatter_out_kernel(const __hip_bfloat16* __restrict__ C,   // [M][N]
                   const int* __restrict__ inv,            // [OUT_DIM]
                   float* __restrict__ out) {              // [M][OUT_DIM]
    const int row = blockIdx.y;
    const int c0 = (blockIdx.x * 256 + threadIdx.x) * 4;
    const __hip_bfloat16* crow = C + (size_t)row * N_DIM;
    const int4 iv = *(const int4*)(inv + c0);
    float4 v;
    v.x = (iv.x >= 0) ? __bfloat162float(crow[iv.x]) : 0.0f;
    v.y = (iv.y >= 0) ? __bfloat162float(crow[iv.y]) : 0.0f;
    v.z = (iv.z >= 0) ? __bfloat162float(crow[iv.z]) : 0.0f;
    v.w = (iv.w >= 0) ? __bfloat162float(crow[iv.w]) : 0.0f;
    *(float4*)(out + (size_t)row * OUT_DIM + c0) = v;
}

// ---------------------------------------------------------------------------
extern "C" void kernel_launch(void* const* d_in, const int* in_sizes, int n_in,
                              void* d_out, int out_size, void* d_ws, size_t ws_size,
                              hipStream_t stream) {
    const float* x      = (const float*)d_in[0];   // [2,4096,4096]
    const float* W_base = (const float*)d_in[1];   // [2048,2048]
    const float* b_base = (const float*)d_in[2];   // [2048]
    const float* lora_A = (const float*)d_in[3];   // [16,2048]
    const float* lora_B = (const float*)d_in[4];   // [2048,16]
    const int* in_idx   = (const int*)d_in[5];     // [2048]
    const int* out_idx  = (const int*)d_in[6];     // [2048]
    float* out = (float*)d_out;                    // [8192,4096]

    const size_t sz_xs = (size_t)M_DIM * K_DIM * 2;   // 32 MB
    const size_t sz_We = (size_t)N_DIM * K_DIM * 2;   //  8 MB
    const size_t sz_C  = (size_t)M_DIM * N_DIM * 2;   // 32 MB
    const size_t sz_inv = (size_t)OUT_DIM * 4;        // 16 KB

    __hip_bfloat16* xs = (__hip_bfloat16*)d_ws;
    __hip_bfloat16* We = (__hip_bfloat16*)((char*)d_ws + sz_xs);
    __hip_bfloat16* Cc = (__hip_bfloat16*)((char*)d_ws + sz_xs + sz_We);
    int* inv           = (int*)((char*)d_ws + sz_xs + sz_We + sz_C);

    fold_w_kernel<<<dim3(K_DIM / 256, N_DIM), 256, 0, stream>>>(W_base, lora_A, lora_B, We);
    gather_cast_kernel<<<M_DIM, 256, 0, stream>>>(x, in_idx, xs);

    if (ws_size >= sz_xs + sz_We + sz_C + sz_inv) {
        // Compact path: GEMM -> bf16 C, then coalesced expand (no memset).
        build_inv_kernel<<<OUT_DIM / 256, 256, 0, stream>>>(out_idx, inv);
        gemm_kernel<true><<<dim3(16, 64), 256, 0, stream>>>(
            xs, We, b_base, out_idx, out, Cc);
        scatter_out_kernel<<<dim3(OUT_DIM / (256 * 4), M_DIM), 256, 0, stream>>>(
            Cc, inv, out);
    } else {
        // Fallback: memset + scattered fp32 epilogue.
        hipMemsetAsync(d_out, 0, (size_t)M_DIM * OUT_DIM * sizeof(float), stream);
        gemm_kernel<false><<<dim3(16, 64), 256, 0, stream>>>(
            xs, We, b_base, out_idx, out, Cc);
    }
}

// Round 4
// 346.380 us; speedup vs baseline: 1.0416x; 1.0416x over previous
//
#include <hip/hip_runtime.h>
#include <hip/hip_bf16.h>
#include <stdint.h>

// Problem constants
#define M_DIM 8192      // 2*4096 flattened batch
#define K_DIM 2048      // ACTIVE (in)
#define N_DIM 2048      // ACTIVE (out)
#define IN_DIM 4096     // ORIG_IN
#define OUT_DIM 4096    // ORIG_OUT
#define SCALING 2.0f    // 32/16

typedef __attribute__((ext_vector_type(8))) short bf16x8_t;  // 8 bf16 = 4 VGPRs
typedef __attribute__((ext_vector_type(4))) float f32x4_t;

__device__ __forceinline__ void load_lds16(const void* gptr, void* lptr) {
    __builtin_amdgcn_global_load_lds(
        (const __attribute__((address_space(1))) uint32_t*)(uintptr_t)gptr,
        (__attribute__((address_space(3))) uint32_t*)(uintptr_t)lptr,
        16, 0, 0);
}

// ---------------------------------------------------------------------------
// Fused prep kernel: three independent, BW-bound jobs share one dispatch so
// their memory traffic overlaps instead of serializing on the stream.
//   blocks [0, M_DIM)                : gather+cast x rows  -> xs (bf16)
//   blocks [M_DIM, M_DIM+8*N_DIM)    : fold LoRA into W    -> We (bf16)
//   blocks [M_DIM+8*N_DIM, +16)      : inverse index map   -> inv (optional)
// ---------------------------------------------------------------------------
__global__ void __launch_bounds__(256)
prep_kernel(const float* __restrict__ x,
            const int* __restrict__ in_idx,
            const float* __restrict__ Wb,
            const float* __restrict__ lA,    // [16][2048]
            const float* __restrict__ lB,    // [2048][16]
            const int* __restrict__ oidx,    // [2048]
            __hip_bfloat16* __restrict__ xs,
            __hip_bfloat16* __restrict__ We,
            int* __restrict__ inv) {
    __shared__ float row[IN_DIM];
    const int bid = blockIdx.x;

    if (bid < M_DIM) {
        // ---- gather + cast (LDS-staged, coalesced both sides) ----
        const float* xrow = x + (size_t)bid * IN_DIM;
        #pragma unroll
        for (int i = 0; i < 4; ++i) {
            const int c = (i * 256 + threadIdx.x) * 4;
            *(float4*)&row[c] = *(const float4*)&xrow[c];
        }
        __syncthreads();
        const int c0 = threadIdx.x * 8;
        int4 i0 = *(const int4*)(in_idx + c0);
        int4 i1 = *(const int4*)(in_idx + c0 + 4);
        union { bf16x8_t v; __hip_bfloat16 h[8]; } u;
        u.h[0] = __float2bfloat16(row[i0.x]);
        u.h[1] = __float2bfloat16(row[i0.y]);
        u.h[2] = __float2bfloat16(row[i0.z]);
        u.h[3] = __float2bfloat16(row[i0.w]);
        u.h[4] = __float2bfloat16(row[i1.x]);
        u.h[5] = __float2bfloat16(row[i1.y]);
        u.h[6] = __float2bfloat16(row[i1.z]);
        u.h[7] = __float2bfloat16(row[i1.w]);
        *(bf16x8_t*)(xs + (size_t)bid * K_DIM + c0) = u.v;
    } else if (bid < M_DIM + 8 * N_DIM) {
        // ---- fold LoRA into base weight, cast to bf16 ----
        const int b = bid - M_DIM;
        const int k = (b & 7) * 256 + threadIdx.x;
        const int o = b >> 3;
        float acc = Wb[(size_t)o * K_DIM + k];
        #pragma unroll
        for (int r = 0; r < 16; ++r)
            acc += SCALING * lB[o * 16 + r] * lA[r * K_DIM + k];
        We[(size_t)o * K_DIM + k] = __float2bfloat16(acc);
    } else {
        // ---- inverse index map (binary search in sorted oidx) ----
        const int c = (bid - (M_DIM + 8 * N_DIM)) * 256 + threadIdx.x; // 0..4095
        int lo = 0, hi = N_DIM;
        while (lo < hi) {
            const int mid = (lo + hi) >> 1;
            if (oidx[mid] < c) lo = mid + 1; else hi = mid;
        }
        inv[c] = (lo < N_DIM && oidx[lo] == c) ? lo : -1;
    }
}

// ---------------------------------------------------------------------------
// GEMM  C = A @ B^T + bias.  Known-good r2 configuration: 128x128 tile,
// BK=64, 4 waves (2x2), each wave 64x64 = 4x4 MFMA 16x16x32 bf16.
// Natural dispatch grid dim3(16,64): HW round-robin over XCDs already pins
// each XCD to 2 n-tiles (B slice L2-resident) AND shares A m-slices between
// adjacent blocks (r2: FETCH ~45MB). global_load_lds 16B staging with XOR
// chunk swizzle: 0 bank conflicts measured (r1/r2).
// COMPACT=true: write bf16 C[M][N] coalesced (bias added).
// ---------------------------------------------------------------------------
template <bool COMPACT>
__global__ void __launch_bounds__(256, 2)
gemm_kernel(const __hip_bfloat16* __restrict__ A,   // [M][K]
            const __hip_bfloat16* __restrict__ B,   // [N][K] (W_eff)
            const float* __restrict__ bias,         // [N]
            const int* __restrict__ oidx,           // [N]
            float* __restrict__ out,                // [M][OUT_DIM] (fallback)
            __hip_bfloat16* __restrict__ Cc)        // [M][N] (compact)
{
    __shared__ __hip_bfloat16 As[128 * 64];
    __shared__ __hip_bfloat16 Bs[128 * 64];

    const int tid  = threadIdx.x;
    const int wave = tid >> 6;
    const int lane = tid & 63;
    const int m0 = blockIdx.y * 128;
    const int n0 = blockIdx.x * 128;

    const int wm = (wave >> 1) * 64;
    const int wn = (wave & 1) * 64;

    const int srow  = tid >> 3;        // 0..31
    const int sslot = tid & 7;         // physical 16B slot within row

    const int r15 = lane & 15;
    const int qd  = lane >> 4;

    f32x4_t acc[4][4] = {};

    for (int k0 = 0; k0 < K_DIM; k0 += 64) {
        #pragma unroll
        for (int it = 0; it < 4; ++it) {
            const int row = it * 32 + srow;
            const int q = sslot ^ (row & 7);
            const __hip_bfloat16* ga = A + (size_t)(m0 + row) * K_DIM + k0 + q * 8;
            const __hip_bfloat16* gb = B + (size_t)(n0 + row) * K_DIM + k0 + q * 8;
            load_lds16(ga, (void*)&As[(it * 32 + wave * 8) * 64]);
            load_lds16(gb, (void*)&Bs[(it * 32 + wave * 8) * 64]);
        }
        __syncthreads();

        #pragma unroll
        for (int s = 0; s < 2; ++s) {
            bf16x8_t af[4], bfr[4];
            #pragma unroll
            for (int i = 0; i < 4; ++i) {
                const int rowa = wm + i * 16 + r15;
                const int pa = (s * 4 + qd) ^ (rowa & 7);
                af[i] = *(const bf16x8_t*)&As[rowa * 64 + pa * 8];
                const int rowb = wn + i * 16 + r15;
                const int pb = (s * 4 + qd) ^ (rowb & 7);
                bfr[i] = *(const bf16x8_t*)&Bs[rowb * 64 + pb * 8];
            }
            #pragma unroll
            for (int i = 0; i < 4; ++i)
                #pragma unroll
                for (int j = 0; j < 4; ++j)
                    acc[i][j] = __builtin_amdgcn_mfma_f32_16x16x32_bf16(
                        af[i], bfr[j], acc[i][j], 0, 0, 0);
        }
        __syncthreads();
    }

    // C/D layout (verified m89/m91): col = lane&15, row = (lane>>4)*4 + reg
    #pragma unroll
    for (int j = 0; j < 4; ++j) {
        const int gn = n0 + wn + j * 16 + r15;
        const float bv = bias[gn];
        if (COMPACT) {
            #pragma unroll
            for (int i = 0; i < 4; ++i) {
                const int gm = m0 + wm + i * 16 + qd * 4;
                #pragma unroll
                for (int r = 0; r < 4; ++r)
                    Cc[(size_t)(gm + r) * N_DIM + gn] =
                        __float2bfloat16(acc[i][j][r] + bv);
            }
        } else {
            const int oc = oidx[gn];
            #pragma unroll
            for (int i = 0; i < 4; ++i) {
                const int gm = m0 + wm + i * 16 + qd * 4;
                #pragma unroll
                for (int r = 0; r < 4; ++r)
                    out[(size_t)(gm + r) * OUT_DIM + oc] = acc[i][j][r] + bv;
            }
        }
    }
}

// ---------------------------------------------------------------------------
// Expand compact C into full output (zeros for unselected cols).
// Fully coalesced float4 writes; replaces the 128 MB memset.
// ---------------------------------------------------------------------------
__global__ void __launch_bounds__(256)
scatter_out_kernel(const __hip_bfloat16* __restrict__ C,   // [M][N]
                   const int* __restrict__ inv,            // [OUT_DIM]
                   float* __restrict__ out) {              // [M][OUT_DIM]
    const int row = blockIdx.y;
    const int c0 = (blockIdx.x * 256 + threadIdx.x) * 4;
    const __hip_bfloat16* crow = C + (size_t)row * N_DIM;
    const int4 iv = *(const int4*)(inv + c0);
    float4 v;
    v.x = (iv.x >= 0) ? __bfloat162float(crow[iv.x]) : 0.0f;
    v.y = (iv.y >= 0) ? __bfloat162float(crow[iv.y]) : 0.0f;
    v.z = (iv.z >= 0) ? __bfloat162float(crow[iv.z]) : 0.0f;
    v.w = (iv.w >= 0) ? __bfloat162float(crow[iv.w]) : 0.0f;
    *(float4*)(out + (size_t)row * OUT_DIM + c0) = v;
}

// ---------------------------------------------------------------------------
extern "C" void kernel_launch(void* const* d_in, const int* in_sizes, int n_in,
                              void* d_out, int out_size, void* d_ws, size_t ws_size,
                              hipStream_t stream) {
    const float* x      = (const float*)d_in[0];   // [2,4096,4096]
    const float* W_base = (const float*)d_in[1];   // [2048,2048]
    const float* b_base = (const float*)d_in[2];   // [2048]
    const float* lora_A = (const float*)d_in[3];   // [16,2048]
    const float* lora_B = (const float*)d_in[4];   // [2048,16]
    const int* in_idx   = (const int*)d_in[5];     // [2048]
    const int* out_idx  = (const int*)d_in[6];     // [2048]
    float* out = (float*)d_out;                    // [8192,4096]

    const size_t sz_xs = (size_t)M_DIM * K_DIM * 2;   // 32 MB
    const size_t sz_We = (size_t)N_DIM * K_DIM * 2;   //  8 MB
    const size_t sz_C  = (size_t)M_DIM * N_DIM * 2;   // 32 MB
    const size_t sz_inv = (size_t)OUT_DIM * 4;        // 16 KB

    __hip_bfloat16* xs = (__hip_bfloat16*)d_ws;
    __hip_bfloat16* We = (__hip_bfloat16*)((char*)d_ws + sz_xs);
    __hip_bfloat16* Cc = (__hip_bfloat16*)((char*)d_ws + sz_xs + sz_We);
    int* inv           = (int*)((char*)d_ws + sz_xs + sz_We + sz_C);

    const bool compact = (ws_size >= sz_xs + sz_We + sz_C + sz_inv);

    // Fused prep: gather blocks + fold blocks (+ inv blocks on compact path).
    const int prep_blocks = M_DIM + 8 * N_DIM + (compact ? 16 : 0);
    prep_kernel<<<prep_blocks, 256, 0, stream>>>(
        x, in_idx, W_base, lora_A, lora_B, out_idx, xs, We, inv);

    if (compact) {
        gemm_kernel<true><<<dim3(N_DIM / 128, M_DIM / 128), 256, 0, stream>>>(
            xs, We, b_base, out_idx, out, Cc);
        scatter_out_kernel<<<dim3(OUT_DIM / (256 * 4), M_DIM), 256, 0, stream>>>(
            Cc, inv, out);
    } else {
        // Fallback: memset + scattered fp32 epilogue.
        hipMemsetAsync(d_out, 0, (size_t)M_DIM * OUT_DIM * sizeof(float), stream);
        gemm_kernel<false><<<dim3(N_DIM / 128, M_DIM / 128), 256, 0, stream>>>(
            xs, We, b_base, out_idx, out, Cc);
    }
}